// Round 1
// baseline (430.841 us; speedup 1.0000x reference)
//
#include <hip/hip_runtime.h>
#include <hip/hip_bf16.h>

typedef __attribute__((ext_vector_type(4))) float          float4v;
typedef __attribute__((ext_vector_type(8))) short          bf16x8;
typedef __attribute__((ext_vector_type(8))) unsigned short ushort8;
typedef __attribute__((ext_vector_type(4))) float          f32x4;

#define NB_   16
#define NF_   256
#define E_    2048
#define T_    4096
#define BN_   64
#define BK_   32

__device__ __forceinline__ unsigned short f2bf(float x) {
    __hip_bfloat16 h = __float2bfloat16(x);   // RNE; compiler packs pairs into v_cvt_pk_bf16_f32
    return __builtin_bit_cast(unsigned short, h);
}

__global__ __launch_bounds__(256, 2)
void mesh_unpool_gemm(const float* __restrict__ features,
                      const float* __restrict__ groups,
                      const float* __restrict__ occur,
                      float* __restrict__ out)
{
    const int b  = blockIdx.y;
    const int n0 = blockIdx.x * BN_;

    const float* __restrict__ fA = features + (size_t)b * NF_ * E_;
    const float* __restrict__ fB = groups   + (size_t)b * E_ * T_;
    const float* __restrict__ fO = occur    + (size_t)b * T_;
    float* __restrict__ fC       = out      + (size_t)b * NF_ * T_;

    // bf16 tiles; 16B "chunks" XOR-swizzled by row to spread banks.
    __shared__ unsigned short As[NF_ * BK_];   // [256][32] (r, k)   16 KB
    __shared__ unsigned short Bs[BN_ * BK_];   // [64][32]  (t, k)    4 KB (k-transposed)

    const int tid  = threadIdx.x;
    const int lane = tid & 63;
    const int wave = tid >> 6;

    const int l15 = lane & 15;
    const int kg  = lane >> 4;              // k-group: frag k-offset = kg*8
    const int sw  = (l15 >> 2) & 3;         // read-side swizzle (== (row>>2)&3 for row = f*16+l15)
    const int kchunk8 = ((kg ^ sw) << 3);   // element offset of this lane's 16B chunk

    // A staging: thread owns row ar, all 32 k's
    const int ar = tid;
    const int sa = (ar >> 2) & 3;
    // B staging: kd = k-pair index (0..15), tq = t-quad (0..15)
    const int kd = tid >> 4;
    const int tq = tid & 15;

    float4v a_reg[8];
    float4v b_reg[2];

    f32x4 acc[4][4];
    #pragma unroll
    for (int i = 0; i < 4; ++i)
        #pragma unroll
        for (int j = 0; j < 4; ++j)
            acc[i][j] = (f32x4){0.f, 0.f, 0.f, 0.f};

    const float* pa_base = fA + (size_t)ar * E_;
    const float* pb_base = fB + (size_t)(kd * 2) * T_ + n0 + tq * 4;

    auto load_tile = [&](int k0) {
        const float* pa = pa_base + k0;
        #pragma unroll
        for (int j = 0; j < 8; ++j)
            a_reg[j] = *(const float4v*)(pa + 4 * j);
        const float* pb = pb_base + (size_t)k0 * T_;
        #pragma unroll
        for (int i = 0; i < 2; ++i)
            b_reg[i] = *(const float4v*)(pb + (size_t)i * T_);
    };

    auto store_tile = [&]() {
        // A: 32 fp32 -> 4 chunks of 8 bf16, swizzled b128 writes
        #pragma unroll
        for (int c = 0; c < 4; ++c) {
            ushort8 pk;
            #pragma unroll
            for (int e = 0; e < 8; ++e)
                pk[e] = f2bf(a_reg[2 * c + (e >> 2)][e & 3]);
            *(ushort8*)&As[(ar << 5) + ((c ^ sa) << 3)] = pk;
        }
        // B: 2x4 register transpose -> 4 packed k-pair b32 writes
        const int cB = (((kd >> 2) ^ (tq & 3)) << 3);
        const int ko = (kd & 3) << 1;
        #pragma unroll
        for (int i = 0; i < 4; ++i) {
            unsigned lo = f2bf(b_reg[0][i]);
            unsigned hi = f2bf(b_reg[1][i]);
            unsigned pair = lo | (hi << 16);
            const int t = tq * 4 + i;
            *(unsigned*)&Bs[(t << 5) + cB + ko] = pair;
        }
    };

    auto compute = [&]() {
        bf16x8 af[4], bfr[4];
        #pragma unroll
        for (int fn = 0; fn < 4; ++fn)
            bfr[fn] = *(const bf16x8*)&Bs[((fn * 16 + l15) << 5) + kchunk8];
        #pragma unroll
        for (int fm = 0; fm < 4; ++fm)
            af[fm] = *(const bf16x8*)&As[((wave * 64 + fm * 16 + l15) << 5) + kchunk8];
        #pragma unroll
        for (int fm = 0; fm < 4; ++fm)
            #pragma unroll
            for (int fn = 0; fn < 4; ++fn)
                acc[fm][fn] = __builtin_amdgcn_mfma_f32_16x16x32_bf16(
                    af[fm], bfr[fn], acc[fm][fn], 0, 0, 0);
    };

    load_tile(0);
    store_tile();
    __syncthreads();

    const int NT = E_ / BK_;   // 64
    for (int kt = 1; kt < NT; ++kt) {
        load_tile(kt * BK_);   // prefetch next tile into regs (overlaps MFMA)
        compute();
        __syncthreads();       // all frag reads done
        store_tile();          // convert + write next tile
        __syncthreads();
    }
    compute();

    // Epilogue: divide by occurrences, store fp32.
    // D layout: col = lane&15, row = (lane>>4)*4 + r  [m89/m91-verified]
    #pragma unroll
    for (int fn = 0; fn < 4; ++fn) {
        const int t = n0 + fn * 16 + l15;
        const float ro = 1.0f / fO[t];
        #pragma unroll
        for (int fm = 0; fm < 4; ++fm) {
            const int rb = wave * 64 + fm * 16 + kg * 4;
            #pragma unroll
            for (int r = 0; r < 4; ++r)
                fC[(size_t)(rb + r) * T_ + t] = acc[fm][fn][r] * ro;
        }
    }
}

extern "C" void kernel_launch(void* const* d_in, const int* in_sizes, int n_in,
                              void* d_out, int out_size, void* d_ws, size_t ws_size,
                              hipStream_t stream) {
    const float* features = (const float*)d_in[0];   // [16][256][2048] fp32
    const float* groups   = (const float*)d_in[1];   // [16][2048][4096] fp32
    const float* occur    = (const float*)d_in[2];   // [16][4096] fp32
    float* outp           = (float*)d_out;           // [16][256][4096] fp32

    dim3 grid(T_ / BN_, NB_);                        // 64 x 16 = 1024 blocks
    mesh_unpool_gemm<<<grid, dim3(256, 1, 1), 0, stream>>>(features, groups, occur, outp);
}

// Round 2
// 181.982 us; speedup vs baseline: 2.3675x; 2.3675x over previous
//
#include <hip/hip_runtime.h>
#include <hip/hip_bf16.h>

typedef __attribute__((ext_vector_type(4))) float          f32x4;
typedef __attribute__((ext_vector_type(8))) short          bf16x8;
typedef __attribute__((ext_vector_type(4))) unsigned short ushort4v;

#define NB_   16
#define NF_   256
#define E_    2048
#define T_    4096
#define BN_   64
#define BK_   32
#define NKT   (E_ / BK_)   // 64 K-steps

__device__ __forceinline__ unsigned short f2bf(float x) {
    __hip_bfloat16 h = __float2bfloat16(x);   // RNE; pairs fuse to v_cvt_pk_bf16_f32
    return __builtin_bit_cast(unsigned short, h);
}

__global__ __launch_bounds__(256, 4)
void mesh_unpool_gemm(const float* __restrict__ features,
                      const float* __restrict__ groups,
                      const float* __restrict__ occur,
                      float* __restrict__ out)
{
    // XCD-grouped decode: xcd = bid&7 (dispatch round-robin); each XCD owns 2
    // batches -> features (2 MB/batch) L2-resident per XCD.
    const int bid = blockIdx.x;
    const int xcd = bid & 7;
    const int s   = bid >> 3;            // 0..127
    const int b   = xcd * 2 + (s >> 6);  // batch
    const int n0  = (s & 63) * BN_;      // t-column block

    const float* __restrict__ fA = features + (size_t)b * NF_ * E_;
    const float* __restrict__ fB = groups   + (size_t)b * E_ * T_;
    const float* __restrict__ fO = occur    + (size_t)b * T_;
    float* __restrict__ fC       = out      + (size_t)b * NF_ * T_;

    // Double-buffered bf16 tiles, 16B-chunk XOR swizzle (chunk ^= (row>>2)&3).
    __shared__ unsigned short As[2][NF_ * BK_];   // [256][32]  2 x 16 KB
    __shared__ unsigned short Bs[2][BN_ * BK_];   // [64][32]   2 x 4 KB  (k-transposed)

    const int tid  = threadIdx.x;
    const int lane = tid & 63;
    const int wave = tid >> 6;
    const int l15  = lane & 15;
    const int kg   = lane >> 4;                 // frag k-offset = kg*8
    const int sw   = (l15 >> 2) & 3;            // read-side swizzle == (row>>2)&3
    const int kchunk8 = ((kg ^ sw) << 3);       // element offset of lane's 16B chunk

    // ---- A staging: coalesced. lane chunk ac of row arw (+32j). ----
    const int ac  = tid & 7;                    // float4 chunk in row (col = ac*4)
    const int arw = tid >> 3;                   // 0..31
    const int sa  = (arw >> 2) & 3;             // constant across j (32j>>2 ≡ 0 mod 4)
    const int a_lds_off = arw * BK_ + (((ac >> 1) ^ sa) << 3) + ((ac & 1) << 2);

    // ---- B staging: adjacent-k row pairs, coalesced. ----
    const int tq = tid & 15;                    // col float4 (t = tq*4..+3)
    const int kp = tid >> 4;                    // k-pair index 0..15 (k = 2kp, 2kp+1)

    f32x4 a_reg[8];
    f32x4 b_reg[2];

    f32x4 acc[4][4];
    #pragma unroll
    for (int i = 0; i < 4; ++i)
        #pragma unroll
        for (int j = 0; j < 4; ++j)
            acc[i][j] = (f32x4){0.f, 0.f, 0.f, 0.f};

    const float* pa_base = fA + (size_t)arw * E_ + ac * 4;
    const float* pb_base = fB + (size_t)(2 * kp) * T_ + n0 + tq * 4;

    auto load_tile = [&](int k0) {
        const float* pa = pa_base + k0;
        #pragma unroll
        for (int j = 0; j < 8; ++j)
            a_reg[j] = *(const f32x4*)(pa + (size_t)j * 32 * E_);
        const float* pb = pb_base + (size_t)k0 * T_;
        b_reg[0] = *(const f32x4*)pb;
        b_reg[1] = *(const f32x4*)(pb + T_);
    };

    auto store_tile = [&](int buf) {
        // A: each float4 -> 4 bf16 (8B) at swizzled half-chunk
        #pragma unroll
        for (int j = 0; j < 8; ++j) {
            ushort4v pk;
            #pragma unroll
            for (int e = 0; e < 4; ++e)
                pk[e] = f2bf(a_reg[j][e]);
            *(ushort4v*)&As[buf][a_lds_off + j * 32 * BK_] = pk;
        }
        // B: register k-transpose -> 4 packed k-pair b32 writes
        #pragma unroll
        for (int i2 = 0; i2 < 4; ++i2) {
            unsigned lo   = f2bf(b_reg[0][i2]);
            unsigned hi   = f2bf(b_reg[1][i2]);
            unsigned pair = lo | (hi << 16);
            const int t   = tq * 4 + i2;        // (t>>2)&3 == tq&3
            *(unsigned*)&Bs[buf][t * BK_ + (((kp >> 2) ^ (tq & 3)) << 3) + ((kp & 3) << 1)] = pair;
        }
    };

    auto compute = [&](int buf) {
        bf16x8 af[4], bfr[4];
        #pragma unroll
        for (int fn = 0; fn < 4; ++fn)
            bfr[fn] = *(const bf16x8*)&Bs[buf][((fn * 16 + l15) << 5) + kchunk8];
        #pragma unroll
        for (int fm = 0; fm < 4; ++fm)
            af[fm] = *(const bf16x8*)&As[buf][((wave * 64 + fm * 16 + l15) << 5) + kchunk8];
        #pragma unroll
        for (int fm = 0; fm < 4; ++fm)
            #pragma unroll
            for (int fn = 0; fn < 4; ++fn)
                acc[fm][fn] = __builtin_amdgcn_mfma_f32_16x16x32_bf16(
                    af[fm], bfr[fn], acc[fm][fn], 0, 0, 0);
    };

    // Prologue
    load_tile(0);
    store_tile(0);
    __syncthreads();

    int cur = 0;
    for (int kt = 1; kt < NKT; ++kt) {
        load_tile(kt * BK_);     // issue next-tile loads (overlap compute)
        compute(cur);            // reads buf[cur]
        store_tile(cur ^ 1);     // vmcnt-wait + cvt + ds_write to other buf
        __syncthreads();         // one barrier per K-step
        cur ^= 1;
    }
    compute(cur);

    // Epilogue: D layout col=lane&15, row=(lane>>4)*4+r
    #pragma unroll
    for (int fn = 0; fn < 4; ++fn) {
        const int t = n0 + fn * 16 + l15;
        const float ro = 1.0f / fO[t];
        #pragma unroll
        for (int fm = 0; fm < 4; ++fm) {
            const int rb = wave * 64 + fm * 16 + kg * 4;
            #pragma unroll
            for (int r = 0; r < 4; ++r)
                fC[(size_t)(rb + r) * T_ + t] = acc[fm][fn][r] * ro;
        }
    }
}

extern "C" void kernel_launch(void* const* d_in, const int* in_sizes, int n_in,
                              void* d_out, int out_size, void* d_ws, size_t ws_size,
                              hipStream_t stream) {
    const float* features = (const float*)d_in[0];   // [16][256][2048] fp32
    const float* groups   = (const float*)d_in[1];   // [16][2048][4096] fp32
    const float* occur    = (const float*)d_in[2];   // [16][4096] fp32
    float* outp           = (float*)d_out;           // [16][256][4096] fp32

    mesh_unpool_gemm<<<dim3(1024), dim3(256, 1, 1), 0, stream>>>(features, groups, occur, outp);
}

// Round 3
// 144.534 us; speedup vs baseline: 2.9809x; 1.2591x over previous
//
#include <hip/hip_runtime.h>
#include <hip/hip_bf16.h>

typedef __attribute__((ext_vector_type(4))) float          f32x4;
typedef __attribute__((ext_vector_type(8))) short          bf16x8;
typedef __attribute__((ext_vector_type(8))) unsigned short ushort8;

#define NB_   16
#define NF_   256
#define E_    2048
#define T_    4096
#define BM_   256
#define BN_   128
#define BK_   32
#define NKT   (E_ / BK_)    // 64 K-steps

__device__ __forceinline__ unsigned short f2bf(float x) {
    __hip_bfloat16 h = __float2bfloat16(x);   // RNE; pairs fuse to v_cvt_pk_bf16_f32
    return __builtin_bit_cast(unsigned short, h);
}

__device__ __forceinline__ void gload_lds16(const float* g, float* l) {
    __builtin_amdgcn_global_load_lds(
        (const __attribute__((address_space(1))) void*)g,
        (__attribute__((address_space(3))) void*)l, 16, 0, 0);
}

__global__ __launch_bounds__(512, 4)
void mesh_unpool_gemm(const float* __restrict__ features,
                      const float* __restrict__ groups,
                      const float* __restrict__ occur,
                      float* __restrict__ out)
{
    // 512 blocks; xcd = bid&7 (dispatch round-robin), 2 batches per XCD.
    const int bid = blockIdx.x;
    const int xcd = bid & 7;
    const int s   = bid >> 3;             // 0..63
    const int b   = xcd * 2 + (s >> 5);   // batch
    const int n0  = (s & 31) * BN_;       // t-column block

    const float* __restrict__ fA = features + (size_t)b * NF_ * E_;
    const float* __restrict__ fB = groups   + (size_t)b * E_ * T_;
    const float* __restrict__ fO = occur    + (size_t)b * T_;
    float* __restrict__ fC       = out      + (size_t)b * NF_ * T_;

    __shared__ float          As[2][BM_ * BK_];   // fp32 [256][32]  2 x 32 KB (linear, src-swizzled)
    __shared__ unsigned short Bs[2][BN_ * BK_];   // bf16 [128][32]  2 x 8 KB  (k-transposed, swizzled)

    const int tid  = threadIdx.x;
    const int lane = tid & 63;
    const int wave = tid >> 6;            // 0..7
    const int wm   = wave >> 1;           // 0..3  (M quadrant)
    const int wn   = wave & 1;            // 0..1  (N half)
    const int l15  = lane & 15;
    const int kg   = lane >> 4;           // 0..3, frag k-offset = kg*8
    const int sw   = (l15 >> 2) & 3;
    const int bko  = (kg ^ sw) << 3;      // B chunk elem offset (shorts)
    const int r7   = l15 & 7;
    const int ac0  = (((2 * kg)     ^ r7) << 2);  // A phys chunk float offsets
    const int ac1  = (((2 * kg + 1) ^ r7) << 2);

    // A staging via global_load_lds: wave w stages rows w*32 + j*8 + (lane>>3),
    // lane fetches pre-swizzled logical chunk (l&7)^(l>>3) so LDS stays linear.
    const int srow = lane >> 3;
    const int schk = (lane & 7) ^ srow;
    const float* aSrc = fA + (size_t)(wave * 32 + srow) * E_ + schk * 4;

    // B staging (reg->cvt->LDS): thread covers cols tq*4..+3, k rows 2kp,2kp+1.
    const int tq = tid & 31;
    const int kp = tid >> 5;
    const float* bSrc = fB + (size_t)(2 * kp) * T_ + n0 + tq * 4;
    const int bSwz = ((kp >> 2) ^ (tq & 3)) << 3;
    const int bKo  = (kp & 3) << 1;

    f32x4 br0[2], br1[2];   // depth-2 B register buffers (named, no runtime idx)
    f32x4 acc[4][4];
    #pragma unroll
    for (int i = 0; i < 4; ++i)
        #pragma unroll
        for (int j = 0; j < 4; ++j)
            acc[i][j] = (f32x4){0.f, 0.f, 0.f, 0.f};

    auto issueA = [&](int buf, int kt) {
        const float* src = aSrc + kt * BK_;
        #pragma unroll
        for (int j = 0; j < 4; ++j)
            gload_lds16(src + (size_t)j * 8 * E_, &As[buf][(wave * 32 + j * 8) * BK_]);
    };
    auto loadB = [&](f32x4 (&br)[2], int kt) {
        const float* src = bSrc + (size_t)kt * BK_ * T_;
        br[0] = *(const f32x4*)src;
        br[1] = *(const f32x4*)(src + T_);
    };
    auto storeB = [&](int buf, f32x4 (&br)[2]) {
        #pragma unroll
        for (int i = 0; i < 4; ++i) {
            unsigned pr = (unsigned)f2bf(br[0][i]) | ((unsigned)f2bf(br[1][i]) << 16);
            *(unsigned*)&Bs[buf][(tq * 4 + i) * BK_ + bSwz + bKo] = pr;
        }
    };
    auto compute = [&](int buf) {
        bf16x8 bfr[4];
        #pragma unroll
        for (int fn = 0; fn < 4; ++fn)
            bfr[fn] = *(const bf16x8*)&Bs[buf][(wn * 64 + fn * 16 + l15) * BK_ + bko];
        #pragma unroll
        for (int fm = 0; fm < 4; ++fm) {
            const float* ar = &As[buf][(wm * 64 + fm * 16 + l15) * BK_];
            f32x4 a0 = *(const f32x4*)(ar + ac0);
            f32x4 a1 = *(const f32x4*)(ar + ac1);
            ushort8 ap;
            #pragma unroll
            for (int e = 0; e < 4; ++e) { ap[e] = f2bf(a0[e]); ap[4 + e] = f2bf(a1[e]); }
            bf16x8 af = __builtin_bit_cast(bf16x8, ap);
            #pragma unroll
            for (int fn = 0; fn < 4; ++fn)
                acc[fm][fn] = __builtin_amdgcn_mfma_f32_16x16x32_bf16(
                    af, bfr[fn], acc[fm][fn], 0, 0, 0);
        }
    };

    // K-step: issue A(kt+1) [4 gload_lds], issue B(kt+2) [2 loads], write B(kt+1),
    // compute(kt), lgkm(0) + counted vmcnt, raw barrier. vmcnt never 0 in steady state.
#define KSTEP(KT, CUR, BLD, BST, HASA, HASB2, VM2)                      \
    {                                                                   \
        if (HASA) issueA((CUR) ^ 1, (KT) + 1);                          \
        __builtin_amdgcn_sched_barrier(0);                              \
        if (HASB2) loadB(BLD, (KT) + 2);                                \
        __builtin_amdgcn_sched_barrier(0);                              \
        if (HASA) storeB((CUR) ^ 1, BST);                               \
        compute(CUR);                                                   \
        asm volatile("s_waitcnt lgkmcnt(0)" ::: "memory");              \
        if (VM2) { asm volatile("s_waitcnt vmcnt(2)" ::: "memory"); }   \
        else     { asm volatile("s_waitcnt vmcnt(0)" ::: "memory"); }   \
        __builtin_amdgcn_s_barrier();                                   \
    }

    // Prologue: A(0) -> buf0, B(0)->br0, B(1)->br1, write B(0), fence, barrier.
    issueA(0, 0);
    __builtin_amdgcn_sched_barrier(0);
    loadB(br0, 0);
    loadB(br1, 1);
    __builtin_amdgcn_sched_barrier(0);
    storeB(0, br0);                         // auto-waits br0 (drains A(0) too)
    asm volatile("s_waitcnt lgkmcnt(0)" ::: "memory");
    asm volatile("s_waitcnt vmcnt(2)" ::: "memory");   // A(0)+B(0) done; B(1) in flight
    __builtin_amdgcn_s_barrier();

    // Steady: kt = 0..61 (hand-unrolled x2: even uses buf0/load br0/store br1).
    for (int p = 0; p < 31; ++p) {
        const int kt = 2 * p;
        KSTEP(kt,     0, br0, br1, true, true, true);
        KSTEP(kt + 1, 1, br1, br0, true, true, true);
    }
    // kt = 62: issue A(63), write B(63) from br1, drain all VMEM at end.
    KSTEP(62, 0, br0, br1, true, false, false);
    // kt = 63: pure compute, no sync needed after.
    compute(1);
#undef KSTEP

    // Epilogue: D layout col=lane&15, row=(lane>>4)*4+r; scale by 1/occ[t].
    #pragma unroll
    for (int fn = 0; fn < 4; ++fn) {
        const int t = n0 + wn * 64 + fn * 16 + l15;
        const float ro = 1.0f / fO[t];
        #pragma unroll
        for (int fm = 0; fm < 4; ++fm) {
            const int rb = wm * 64 + fm * 16 + kg * 4;
            #pragma unroll
            for (int r = 0; r < 4; ++r)
                fC[(size_t)(rb + r) * T_ + t] = acc[fm][fn][r] * ro;
        }
    }
}

extern "C" void kernel_launch(void* const* d_in, const int* in_sizes, int n_in,
                              void* d_out, int out_size, void* d_ws, size_t ws_size,
                              hipStream_t stream) {
    const float* features = (const float*)d_in[0];   // [16][256][2048] fp32
    const float* groups   = (const float*)d_in[1];   // [16][2048][4096] fp32
    const float* occur    = (const float*)d_in[2];   // [16][4096] fp32
    float* outp           = (float*)d_out;           // [16][256][4096] fp32

    mesh_unpool_gemm<<<dim3(512), dim3(512, 1, 1), 0, stream>>>(features, groups, occur, outp);
}